// Round 1
// 284.800 us; speedup vs baseline: 1.0857x; 1.0857x over previous
//
#include <hip/hip_runtime.h>
#include <hip/hip_bf16.h>
#include <stdint.h>

#define DEV __device__ __forceinline__

typedef __attribute__((ext_vector_type(8))) short short8;    // 8 bf16 (MFMA A/B frag)
typedef __attribute__((ext_vector_type(4))) float floatx4;   // MFMA C/D frag

constexpr int TM  = 64;     // rows per block
constexpr int NB  = 131072; // batch
constexpr int AST = 264;    // act row stride (bf16 elems)

// ---- packed bf16 weight layout in d_ws (element offsets) ----
// Transposed-GEMM scheme: weights are the A operand now. A and B fragment
// layouts are mirror images, so the (k,n)->lane packing is UNCHANGED; only
// the consumer-side column permutations (applied when activations were
// written ln*4+ct) are now identity, since C's register dim carries n.
constexpr int OFF_W1 = 0;        // 4w x 7kc x 4nt x 512   (K=224: 199 state + td + BIAS@200)
constexpr int OFF_W2 = 57344;    // 4w x 8 x 4 x 512       (K=256, N=256)
constexpr int OFF_W3 = 122880;   // 4w x 8 x 2 x 512       (K=256, N=128)
constexpr int OFF_WH = 155648;   // 4h x 4 x 4 x 512       (K=128, N=64; h=0..2 adv, h=3 value)
constexpr int OFF_WA2= 188416;   // 3h x 2 x 2 x 512       (K=64,  N=32)
constexpr int NWQ    = 194560;

// cq layout: all float4-loadable bases 16B-aligned (BA1 moved 2177->2180)
constexpr int C_B1=0, C_G1=256, C_BE1=512, C_B2=768, C_G2=1024, C_BE2=1280,
  C_B3=1536, C_G3=1664, C_BE3=1792, C_BV1=1920, C_GV=1984, C_BEV=2048,
  C_WV2=2112, C_BV2=2176, C_BA1=2180, C_GA=2372, C_BEA=2564, C_BA2=2756;
constexpr int NCONST=2852;

struct Ptrs {
  const float *state,*td,*W1,*b1,*g1,*be1,*W2,*b2,*g2,*be2,*W3,*b3,*g3,*be3,
    *Wv1,*bv1,*gv,*bev,*Wv2,*bv2,*Wa1,*ba1,*ga,*bea,*Wa2,*ba2;
  const int *et;
};

DEV unsigned short f2bf(float x){
  uint32_t u = __float_as_uint(x);
  u += 0x7fffu + ((u>>16)&1u);
  return (unsigned short)(u>>16);
}
DEV uint32_t f2bf_pk(float a, float b){
  float2 f2; f2.x=a; f2.y=b;
  __hip_bfloat162 h = __float22bfloat162_rn(f2);
  union { __hip_bfloat162 h; uint32_t u; } cv; cv.h = h;
  return cv.u;
}

// =====================================================================
// prep: quantize + transpose + pack weights (W1 carries b1 at k==200)
// Consumer-side swizzles removed (activations now written in natural order).
// =====================================================================
__global__ void prep_kernel(Ptrs p, unsigned short* __restrict__ wq, float* __restrict__ cq){
  int idx = blockIdx.x*256 + threadIdx.x;
  if (idx < NWQ) {
    float v = 0.f;
    if (idx < OFF_W2) {                       // W1 (+bias row at k=200)
      int e = idx, w = e/14336, r = e%14336;
      int kc = r>>11, ct=(r>>9)&3, l=(r>>3)&63, j=r&7;
      int n = w*64 + ct*16 + (l&15);
      int k = kc*32 + (l>>4)*8 + j;
      if (k < 200) v = p.W1[k*256 + n];
      else if (k == 200) v = p.b1[n];
    } else if (idx < OFF_W3) {                // W2
      int e = idx-OFF_W2, w=e>>14, r=e&16383;
      int kc=r>>11, ct=(r>>9)&3, l=(r>>3)&63, j=r&7;
      int n = w*64 + ct*16 + (l&15);
      int k = kc*32 + (l>>4)*8 + j;
      v = p.W2[k*256 + n];
    } else if (idx < OFF_WH) {                // W3
      int e = idx-OFF_W3, w=e>>13, r=e&8191;
      int kc=r>>10, ct=(r>>9)&1, l=(r>>3)&63, j=r&7;
      int n = w*32 + ct*16 + (l&15);
      int k = kc*32 + (l>>4)*8 + j;
      v = p.W3[k*128 + n];
    } else if (idx < OFF_WA2) {               // Wv1/Wa1
      int e = idx-OFF_WH, h=e>>13, r=e&8191;
      int kc=r>>11, ct=(r>>9)&3, l=(r>>3)&63, j=r&7;
      int n = ct*16 + (l&15);
      int k = kc*32 + (l>>4)*8 + j;
      v = (h<3) ? p.Wa1[h*8192 + k*64 + n] : p.Wv1[k*64 + n];
    } else {                                  // Wa2
      int e = idx-OFF_WA2, h=e>>11, r=e&2047;
      int kc=r>>10, ct=(r>>9)&1, l=(r>>3)&63, j=r&7;
      int n = ct*16 + (l&15);
      int k = kc*32 + (l>>4)*8 + j;
      v = p.Wa2[h*2048 + k*32 + n];
    }
    wq[idx] = f2bf(v);
  } else if (idx < NWQ + NCONST) {
    int ci = idx - NWQ;
    float v;
    if      (ci < 256)  v = p.b1[ci];
    else if (ci < 512)  v = p.g1[ci-256];
    else if (ci < 768)  v = p.be1[ci-512];
    else if (ci < 1024) v = p.b2[ci-768];
    else if (ci < 1280) v = p.g2[ci-1024];
    else if (ci < 1536) v = p.be2[ci-1280];
    else if (ci < 1664) v = p.b3[ci-1536];
    else if (ci < 1792) v = p.g3[ci-1664];
    else if (ci < 1920) v = p.be3[ci-1792];
    else if (ci < 1984) v = p.bv1[ci-1920];
    else if (ci < 2048) v = p.gv[ci-1984];
    else if (ci < 2112) v = p.bev[ci-2048];
    else if (ci < 2176) v = p.Wv2[ci-2112];
    else if (ci < 2180) v = (ci==2176) ? p.bv2[0] : 0.f;   // bv2 + pad
    else if (ci < 2372) v = p.ba1[ci-2180];
    else if (ci < 2564) v = p.ga[ci-2372];
    else if (ci < 2756) v = p.bea[ci-2564];
    else                v = p.ba2[ci-2756];
    cq[ci] = v;
  }
}

// =====================================================================
// device helpers — transposed orientation: A=weights, B=activations.
// C layout: col = batch row (lane&15), row = n = (lane>>4)*4 + reg.
// =====================================================================
template<int N>
DEV void loadB(short8 (&B)[N], const unsigned short* __restrict__ src, int lane){
  #pragma unroll
  for (int i=0;i<N;i++) B[i] = *(const short8*)(src + i*512 + lane*8);
}

template<int RT>
DEV void zeroAccT(floatx4 (&acc)[RT][4]){
  const floatx4 z = {0.f,0.f,0.f,0.f};
  #pragma unroll
  for (int rt=0;rt<RT;rt++)
    #pragma unroll
    for (int ct=0;ct<4;ct++) acc[rt][ct]=z;
}

// acc[rt][ct]: rt = n-tile (reg dim rows), ct = batch-tile (lane dim cols)
template<int KC,int RT>
DEV void runGemmT(floatx4 (&acc)[RT][4], const short8 (&Bw)[KC*RT],
                  const unsigned short* aBase, int aOff){
  #pragma unroll
  for (int kc=0;kc<KC;kc++){
    short8 a[4];
    #pragma unroll
    for (int ct=0;ct<4;ct++)
      a[ct] = *(const short8*)(aBase + ct*16*AST + aOff + kc*32);
    #pragma unroll
    for (int rt=0;rt<RT;rt++)
      #pragma unroll
      for (int ct=0;ct<4;ct++)
        acc[rt][ct] = __builtin_amdgcn_mfma_f32_16x16x32_bf16(Bw[kc*RT+rt], a[ct], acc[rt][ct], 0,0,0);
  }
}

// bias fold (in place) + per-batch-row (s,ss): 16 in-register adds per ct,
// then 2 shfl steps across q-groups, atomic accumulate across waves.
template<int RT,bool BIAS>
DEV void statsT(floatx4 (&acc)[RT][4], const float* __restrict__ cq, int bo,
                float* sbuf, float* ssbuf, int q, int ln){
  if constexpr (BIAS){
    #pragma unroll
    for (int rt=0;rt<RT;rt++){
      floatx4 b4 = *(const floatx4*)(cq + bo + rt*16 + q*4);
      #pragma unroll
      for (int ct=0;ct<4;ct++) acc[rt][ct] += b4;
    }
  }
  #pragma unroll
  for (int ct=0;ct<4;ct++){
    float s=0.f, ss=0.f;
    #pragma unroll
    for (int rt=0;rt<RT;rt++)
      #pragma unroll
      for (int r=0;r<4;r++){ float v=acc[rt][ct][r]; s+=v; ss+=v*v; }
    s += __shfl_xor(s,16); ss += __shfl_xor(ss,16);
    s += __shfl_xor(s,32); ss += __shfl_xor(ss,32);
    if (q==0){
      atomicAdd(&sbuf[ct*16+ln], s);
      atomicAdd(&ssbuf[ct*16+ln], ss);
    }
  }
}

// LN apply + relu + natural-order packed bf16 write (4 rsqrt per lane)
template<int RT>
DEV void lnWriteT(const floatx4 (&acc)[RT][4], const float* __restrict__ cq, int go, int beo,
                  const float* sbuf, const float* ssbuf, float invN,
                  unsigned short* act_, int colBase, int q, int ln){
  float mu[4], rs[4];
  #pragma unroll
  for (int ct=0;ct<4;ct++){
    float sv = sbuf[ct*16+ln], ssv = ssbuf[ct*16+ln];
    mu[ct] = sv*invN;
    rs[ct] = rsqrtf(ssv*invN - mu[ct]*mu[ct] + 1e-5f);
  }
  #pragma unroll
  for (int rt=0;rt<RT;rt++){
    floatx4 g4  = *(const floatx4*)(cq + go  + rt*16 + q*4);
    floatx4 be4 = *(const floatx4*)(cq + beo + rt*16 + q*4);
    #pragma unroll
    for (int ct=0;ct<4;ct++){
      float y[4];
      #pragma unroll
      for (int r=0;r<4;r++)
        y[r] = fmaxf((acc[rt][ct][r]-mu[ct])*rs[ct]*g4[r]+be4[r], 0.f);
      uint2 pk; pk.x = f2bf_pk(y[0],y[1]); pk.y = f2bf_pk(y[2],y[3]);
      *(uint2*)(act_ + (ct*16+ln)*AST + colBase + rt*16 + q*4) = pk;
    }
  }
}

// =====================================================================
// fused forward, transposed-C orientation. 8 barriers as before.
// =====================================================================
__global__ __launch_bounds__(256,4) void dqn_main(
    const float* __restrict__ state, const float* __restrict__ td,
    const int* __restrict__ et, const unsigned short* __restrict__ wq,
    const float* __restrict__ cq, float* __restrict__ out)
{
  __shared__ __align__(16) unsigned short act[TM*AST];   // 33 KB
  __shared__ float sstat[2][2][64];                       // [pp][s/ss][row] 1 KB
  __shared__ float vbuf[64];
  __shared__ int   etl[64];

  const int tid=threadIdx.x, w=tid>>6, lane=tid&63, q=lane>>4, ln=lane&15;
  const int rowBlk = blockIdx.x*TM;

  // ---- stage x = [state(199) | td@199 | 1.0@200 | 0 pad to 223] ----
  // 8-elem chunks: 64 rows x 28 chunks = 1792 tasks = exactly 7 iters.
  {
    ((float*)sstat)[tid] = 0.f;
    const float* sbase = state + (size_t)rowBlk*199;
    #pragma unroll
    for (int it=0; it<7; ++it){
      int t = tid + it*256;
      int r = t/28, c = t - r*28;          // magic-div, once per 8 elems
      unsigned short* dst = act + r*AST + c*8;
      if (c < 25){
        const float* src = sbase + r*199 + c*8;
        float v0=src[0], v1=src[1], v2=src[2], v3=src[3];
        float v4=src[4], v5=src[5], v6=src[6];
        int o7 = (c==24)? 198 : c*8+7;     // avoid OOB speculation at row end
        float s7 = sbase[r*199 + o7];
        float v7 = (c==24)? td[rowBlk+r] : s7;
        uint4 pk;
        pk.x=f2bf_pk(v0,v1); pk.y=f2bf_pk(v2,v3);
        pk.z=f2bf_pk(v4,v5); pk.w=f2bf_pk(v6,v7);
        *(uint4*)dst = pk;
      } else {
        uint4 pk{0u,0u,0u,0u};
        if (c==25) pk.x = 0x3F80u;         // col 200 = bf16(1.0) * W1 bias row
        *(uint4*)dst = pk;
      }
    }
    if (tid < 64) etl[tid] = et[rowBlk+tid];
  }
  __syncthreads();                                        // B1

  const unsigned short* aBase = act + ln*AST + q*8;
  floatx4 acc[4][4];

  // ---- L1: x(224 incl bias row) -> h1(256); stats pp0 ----
  {
    short8 Bw[28];
    loadB<28>(Bw, wq + OFF_W1 + w*14336, lane);
    zeroAccT<4>(acc);
    runGemmT<7,4>(acc, Bw, aBase, 0);
  }
  statsT<4,false>(acc, cq, 0, sstat[0][0], sstat[0][1], q, ln);
  __syncthreads();                                        // B2
  lnWriteT<4>(acc, cq, C_G1+w*64, C_BE1+w*64, sstat[0][0], sstat[0][1], 1.f/256.f, act, w*64, q, ln);
  __syncthreads();                                        // B3

  // ---- L2: h1(256) -> h2(256); stats pp1 ----
  {
    short8 Bw[32];
    loadB<32>(Bw, wq + OFF_W2 + w*16384, lane);
    zeroAccT<4>(acc);
    runGemmT<8,4>(acc, Bw, aBase, 0);
  }
  statsT<4,true>(acc, cq, C_B2+w*64, sstat[1][0], sstat[1][1], q, ln);
  __syncthreads();                                        // B4
  if (tid < 128) ((float*)sstat[0])[tid] = 0.f;           // re-zero pp0
  lnWriteT<4>(acc, cq, C_G2+w*64, C_BE2+w*64, sstat[1][0], sstat[1][1], 1.f/256.f, act, w*64, q, ln);
  __syncthreads();                                        // B5

  // ---- L3: h2(256) -> f(128), wave n-cols [32w,32w+32); stats pp0 ----
  floatx4 acc3[2][4];
  {
    short8 Bw[16];
    loadB<16>(Bw, wq + OFF_W3 + w*8192, lane);
    zeroAccT<2>(acc3);
    runGemmT<8,2>(acc3, Bw, aBase, 0);
  }
  statsT<2,true>(acc3, cq, C_B3+w*32, sstat[0][0], sstat[0][1], q, ln);
  __syncthreads();                                        // B6
  lnWriteT<2>(acc3, cq, C_G3+w*32, C_BE3+w*32, sstat[0][0], sstat[0][1], 1.f/128.f, act, w*32, q, ln);
  __syncthreads();                                        // B7

  // ---- heads: wave w = head w (0..2 adv, 3 value). f(128)->64, LN in-wave ----
  {
    short8 Bh[16];
    loadB<16>(Bh, wq + OFF_WH + w*8192, lane);
    zeroAccT<4>(acc);
    runGemmT<4,4>(acc, Bh, aBase, 0);
  }
  {
    const int bo = (w<3)? C_BA1+w*64 : C_BV1;
    const int go = (w<3)? C_GA +w*64 : C_GV;
    const int beo= (w<3)? C_BEA+w*64 : C_BEV;
    #pragma unroll
    for (int rt=0;rt<4;rt++){
      floatx4 b4 = *(const floatx4*)(cq + bo + rt*16 + q*4);
      #pragma unroll
      for (int ct=0;ct<4;ct++) acc[rt][ct] += b4;
    }
    float mu[4], rs[4];
    #pragma unroll
    for (int ct=0;ct<4;ct++){
      float s=0.f, ss=0.f;
      #pragma unroll
      for (int rt=0;rt<4;rt++)
        #pragma unroll
        for (int r=0;r<4;r++){ float v=acc[rt][ct][r]; s+=v; ss+=v*v; }
      s += __shfl_xor(s,16); ss += __shfl_xor(ss,16);
      s += __shfl_xor(s,32); ss += __shfl_xor(ss,32);
      mu[ct]=s*(1.f/64.f);
      rs[ct]=rsqrtf(ss*(1.f/64.f)-mu[ct]*mu[ct]+1e-5f);
    }
    #pragma unroll
    for (int rt=0;rt<4;rt++){
      floatx4 g4  = *(const floatx4*)(cq + go  + rt*16 + q*4);
      floatx4 be4 = *(const floatx4*)(cq + beo + rt*16 + q*4);
      #pragma unroll
      for (int ct=0;ct<4;ct++)
        #pragma unroll
        for (int r=0;r<4;r++)
          acc[rt][ct][r] = fmaxf((acc[rt][ct][r]-mu[ct])*rs[ct]*g4[r]+be4[r], 0.f);
    }
    if (w==3){
      float bv2v = cq[C_BV2];
      floatx4 wv4[4];
      #pragma unroll
      for (int rt=0;rt<4;rt++) wv4[rt] = *(const floatx4*)(cq + C_WV2 + rt*16 + q*4);
      #pragma unroll
      for (int ct=0;ct<4;ct++){
        float dot=0.f;
        #pragma unroll
        for (int rt=0;rt<4;rt++)
          #pragma unroll
          for (int r=0;r<4;r++) dot += acc[rt][ct][r]*wv4[rt][r];
        dot += __shfl_xor(dot,16);
        dot += __shfl_xor(dot,32);
        if (q==0) vbuf[ct*16+ln] = dot + bv2v;
      }
    }
  }
  __syncthreads();                                        // B8: f-reads done; vbuf visible

  // adv heads: write ha into own cols [64w,64w+64) (same-wave reuse only),
  // a2 GEMM, dueling combine, predicated float4 out stores.
  if (w<3){
    #pragma unroll
    for (int rt=0;rt<4;rt++)
      #pragma unroll
      for (int ct=0;ct<4;ct++){
        uint2 pk;
        pk.x = f2bf_pk(acc[rt][ct][0], acc[rt][ct][1]);
        pk.y = f2bf_pk(acc[rt][ct][2], acc[rt][ct][3]);
        *(uint2*)(act + (ct*16+ln)*AST + 64*w + rt*16 + q*4) = pk;
      }
    short8 B2[4];
    loadB<4>(B2, wq + OFF_WA2 + w*2048, lane);
    floatx4 acc2[2][4];
    zeroAccT<2>(acc2);
    runGemmT<2,2>(acc2, B2, aBase, 64*w);
    #pragma unroll
    for (int rt=0;rt<2;rt++){
      floatx4 b4 = *(const floatx4*)(cq + C_BA2 + w*32 + rt*16 + q*4);
      #pragma unroll
      for (int ct=0;ct<4;ct++) acc2[rt][ct] += b4;
    }
    #pragma unroll
    for (int ct=0;ct<4;ct++){
      float sm=0.f;
      #pragma unroll
      for (int rt=0;rt<2;rt++)
        #pragma unroll
        for (int r=0;r<4;r++) sm += acc2[rt][ct][r];
      sm += __shfl_xor(sm,16);
      sm += __shfl_xor(sm,32);
      int b = ct*16+ln;
      if (etl[b]==w){
        float vm = vbuf[b] - sm*(1.f/32.f);
        #pragma unroll
        for (int rt=0;rt<2;rt++){
          floatx4 o = acc2[rt][ct];
          o[0]+=vm; o[1]+=vm; o[2]+=vm; o[3]+=vm;
          *(floatx4*)(out + (size_t)(rowBlk+b)*32 + rt*16 + q*4) = o;
        }
      }
    }
  }
}

// =====================================================================
extern "C" void kernel_launch(void* const* d_in, const int* in_sizes, int n_in,
                              void* d_out, int out_size, void* d_ws, size_t ws_size,
                              hipStream_t stream)
{
  Ptrs p;
  p.state=(const float*)d_in[0];  p.td =(const float*)d_in[1];
  p.W1 =(const float*)d_in[2];  p.b1 =(const float*)d_in[3];  p.g1 =(const float*)d_in[4];  p.be1=(const float*)d_in[5];
  p.W2 =(const float*)d_in[6];  p.b2 =(const float*)d_in[7];  p.g2 =(const float*)d_in[8];  p.be2=(const float*)d_in[9];
  p.W3 =(const float*)d_in[10]; p.b3 =(const float*)d_in[11]; p.g3 =(const float*)d_in[12]; p.be3=(const float*)d_in[13];
  p.Wv1=(const float*)d_in[14]; p.bv1=(const float*)d_in[15]; p.gv =(const float*)d_in[16]; p.bev=(const float*)d_in[17];
  p.Wv2=(const float*)d_in[18]; p.bv2=(const float*)d_in[19];
  p.Wa1=(const float*)d_in[20]; p.ba1=(const float*)d_in[21]; p.ga =(const float*)d_in[22]; p.bea=(const float*)d_in[23];
  p.Wa2=(const float*)d_in[24]; p.ba2=(const float*)d_in[25];
  p.et =(const int*)d_in[26];

  unsigned short* wq = (unsigned short*)d_ws;
  float* cq = (float*)((char*)d_ws + (size_t)NWQ*2);

  const int prepN = NWQ + NCONST;
  hipLaunchKernelGGL(prep_kernel, dim3((prepN+255)/256), dim3(256), 0, stream, p, wq, cq);
  hipLaunchKernelGGL(dqn_main, dim3(NB/TM), dim3(256), 0, stream,
                     p.state, p.td, p.et, (const unsigned short*)wq, (const float*)cq, (float*)d_out);
}